// Round 10
// baseline (191.910 us; speedup 1.0000x reference)
//
#include <hip/hip_runtime.h>
#include <hip/hip_bf16.h>
#include <stdint.h>

#define B_   8
#define L_   2048
#define D_   768
#define H_   16
#define DH   48
#define E_   300
#define EP   320   // E padded to 320 (zeros -> relu(0)=0, exact no-op)
#define KP   64    // dh padded to 64 for K of MFMA1
#define ACH  8     // phaseA L-chunks
#define N1T  (128 * DH * EP)   // one partial-out1 plane
#define NT_  24    // GEMM K-steps (768/32)

typedef __bf16 bf16;
typedef __bf16 bf16x8 __attribute__((ext_vector_type(8)));
typedef __bf16 bf16x4 __attribute__((ext_vector_type(4)));
typedef float  f32x4  __attribute__((ext_vector_type(4)));

typedef const __attribute__((address_space(1))) uint32_t guint;
typedef __attribute__((address_space(3))) uint32_t luint;

__device__ __forceinline__ f32x4 mfma16(bf16x8 a, bf16x8 b, f32x4 c) {
  return __builtin_amdgcn_mfma_f32_16x16x32_bf16(a, b, c, 0, 0, 0);
}

// ---- prep: cast q,k fp32 -> bf16 (enables global_load_lds for GEMM A) ----
__global__ __launch_bounds__(256) void k_cast(const float* __restrict__ q,
                                              const float* __restrict__ k,
                                              bf16* __restrict__ qc,
                                              bf16* __restrict__ kc) {
  const float* src = blockIdx.y ? k : q;
  bf16* dst = blockIdx.y ? kc : qc;
  const int n8 = B_ * L_ * D_ / 8;
  for (int i = blockIdx.x * 256 + threadIdx.x; i < n8; i += gridDim.x * 256) {
    float4 f0 = *(const float4*)(src + (size_t)i * 8);
    float4 f1 = *(const float4*)(src + (size_t)i * 8 + 4);
    bf16x8 v;
    v[0] = (bf16)f0.x; v[1] = (bf16)f0.y; v[2] = (bf16)f0.z; v[3] = (bf16)f0.w;
    v[4] = (bf16)f1.x; v[5] = (bf16)f1.y; v[6] = (bf16)f1.z; v[7] = (bf16)f1.w;
    *(bf16x8*)(dst + (size_t)i * 8) = v;
  }
}

// ---- prep (merged): W transpose-cast x2 + memory pad, one launch ----
__global__ __launch_bounds__(256) void k_prep(
    const float* __restrict__ Wq, const float* __restrict__ Wv,
    const float* __restrict__ M, bf16* __restrict__ WqT,
    bf16* __restrict__ WvT, bf16* __restrict__ MP) {
  int bid = blockIdx.x;
  if (bid < 4608) {                       // 2 x 2304: W transpose-cast
    int which = bid / 2304;
    int idx = (bid % 2304) * 256 + threadIdx.x;
    int n = idx / D_, k = idx % D_;
    const float* W = which ? Wv : Wq;
    bf16* WT = which ? WvT : WqT;
    WT[n * D_ + k] = (bf16)W[k * D_ + n];
  } else {                                // 1280: memory -> MP [h][320][64]
    int idx = (bid - 4608) * 256 + threadIdx.x;
    int h = idx / (EP * KP);
    int r = idx % (EP * KP);
    int e = r / KP, d = r % KP;
    float v = (e < E_ && d < DH) ? M[(e * H_ + h) * DH + d] : 0.f;
    MP[idx] = (bf16)v;
  }
}

// ---- projection GEMM: C[16384x768] = A(bf16) @ W + bias ----
// 256 thr / 4 waves (2x2), 64x64 per wave. BM=BN=128, BK=32.
// T4: BOTH operands via global_load_lds, 3-deep LDS (16KB/slice, 48KB),
// staged 2 ahead; per iter s_waitcnt vmcnt(4) (slice t+1 stays in flight
// across the raw barrier), lgkmcnt(0)-only barrier. 3 blocks/CU.
// K-loop fully unrolled (static buf indices); T5 setprio around MFMAs.
__global__ __launch_bounds__(256, 3) void k_gemm(
    const bf16* __restrict__ A0, const bf16* __restrict__ A1,
    const bf16* __restrict__ WT0, const bf16* __restrict__ WT1,
    const float* __restrict__ b0, const float* __restrict__ b1,
    bf16* __restrict__ outQ, bf16* __restrict__ outVT) {
  __shared__ bf16 As[3][128 * 32];   // 3 x 8 KB
  __shared__ bf16 Bs[3][128 * 32];   // 3 x 8 KB
  const int tid = threadIdx.x, lane = tid & 63, w = tid >> 6;
  const int wr = w >> 1, wc = w & 1;
  const int lr = lane & 15, lq = lane >> 4;
  // XCD-chunked swizzle: 768 = 8 XCDs x 96 (bijective); an m-panel's 6
  // n-blocks run consecutively on one XCD -> A panel (196KB bf16) L2-hot.
  const int bid = blockIdx.x;
  const int j = (bid & 7) * 96 + (bid >> 3);
  const int n0 = (j % 6) * 128, m0 = (j / 6) * 128;
  const int mode = blockIdx.y;
  const bf16* A = mode ? A1 : A0;
  const bf16* WT = mode ? WT1 : WT0;
  const float* bias = mode ? b1 : b0;

  // one K-slice = A 8KB + B 8KB = 4 gload_lds per wave (2 A + 2 B)
  auto stage = [&](int buf, int k0) {
#pragma unroll
    for (int p = 0; p < 2; ++p) {          // A: rows idx>>2, chunk idx&3
      int idx = tid + p * 256;
      int row = idx >> 2, ct = idx & 3;
      int gc = ct ^ ((row >> 1) & 3);      // pre-swizzled source chunk
      const bf16* src = A + (size_t)(m0 + row) * D_ + k0 + gc * 8;
      __builtin_amdgcn_global_load_lds((guint*)src,
          (luint*)&As[buf][(p * 256 + w * 64) * 8], 16, 0, 0);
    }
#pragma unroll
    for (int p = 0; p < 2; ++p) {          // B: same pattern
      int idx = tid + p * 256;
      int row = idx >> 2, ct = idx & 3;
      int gc = ct ^ ((row >> 1) & 3);
      const bf16* src = WT + (size_t)(n0 + row) * D_ + k0 + gc * 8;
      __builtin_amdgcn_global_load_lds((guint*)src,
          (luint*)&Bs[buf][(p * 256 + w * 64) * 8], 16, 0, 0);
    }
  };

  f32x4 acc[4][4] = {};

  // prologue: slices 0 and 1 in flight (8 outstanding per wave)
  stage(0, 0);
  stage(1, 32);

#pragma unroll
  for (int t = 0; t < NT_; ++t) {
    const int cur = t % 3;
    // retire slice t (oldest 4), keep slice t+1 flying; lgkm covers our
    // own prior frag reads (WAR vs the stage below).
    if (t + 1 < NT_) asm volatile("s_waitcnt vmcnt(4) lgkmcnt(0)" ::: "memory");
    else             asm volatile("s_waitcnt vmcnt(0) lgkmcnt(0)" ::: "memory");
    __builtin_amdgcn_s_barrier();
    __builtin_amdgcn_sched_barrier(0);
    if (t + 2 < NT_) stage((t + 2) % 3, (t + 2) * 32);

    bf16x8 af[4], bfr[4];
#pragma unroll
    for (int mi = 0; mi < 4; ++mi) {
      int row = wr * 64 + mi * 16 + lr;
      af[mi] = *(const bf16x8*)&As[cur][row * 32 + ((lq ^ ((row >> 1) & 3)) * 8)];
    }
#pragma unroll
    for (int ni = 0; ni < 4; ++ni) {
      int row = wc * 64 + ni * 16 + lr;
      bfr[ni] = *(const bf16x8*)&Bs[cur][row * 32 + ((lq ^ ((row >> 1) & 3)) * 8)];
    }
    __builtin_amdgcn_s_setprio(1);
#pragma unroll
    for (int mi = 0; mi < 4; ++mi)
#pragma unroll
      for (int ni = 0; ni < 4; ++ni)
        acc[mi][ni] = mfma16(af[mi], bfr[ni], acc[mi][ni]);
    __builtin_amdgcn_s_setprio(0);
  }

  float bs[4];
#pragma unroll
  for (int ni = 0; ni < 4; ++ni) bs[ni] = bias[n0 + wc * 64 + ni * 16 + lr];

  if (mode == 0) {
#pragma unroll
    for (int mi = 0; mi < 4; ++mi)
#pragma unroll
      for (int ni = 0; ni < 4; ++ni) {
        int m = m0 + wr * 64 + mi * 16 + lq * 4;
        int n = n0 + wc * 64 + ni * 16 + lr;
#pragma unroll
        for (int r = 0; r < 4; ++r)
          outQ[(size_t)(m + r) * D_ + n] = (bf16)(acc[mi][ni][r] + bs[ni]);
      }
  } else {
#pragma unroll
    for (int mi = 0; mi < 4; ++mi)
#pragma unroll
      for (int ni = 0; ni < 4; ++ni) {
        int mb = m0 + wr * 64 + mi * 16 + lq * 4;
        int n = n0 + wc * 64 + ni * 16 + lr;
        int bhd = (mb >> 11) * H_ + n / DH;
        int d = n % DH;
        int l = mb & (L_ - 1);
        bf16x4 v;
#pragma unroll
        for (int r = 0; r < 4; ++r) v[r] = (bf16)(acc[mi][ni][r] + bs[ni]);
        *(bf16x4*)&outVT[((size_t)bhd * DH + d) * L_ + l] = v;
      }
  }
}

// ---- phase A: partial out1 = relu(mem @ Q^T) @ V over an L/8 chunk ----
// 1D grid 1024 = 8 XCDs x 128; same-bh chunks grouped per XCD (L2 reuse
// of Qb/VT panels + mem head slice). Writes bf16 partial O1P.
__global__ __launch_bounds__(256) void k_phaseA(
    const bf16* __restrict__ Qb, const bf16* __restrict__ VT,
    const bf16* __restrict__ MP, bf16* __restrict__ O1P) {
  __shared__ bf16 Qs[2][32 * 88];
  __shared__ bf16 Vs[2][48 * 40];
  __shared__ bf16 Ss[EP * 40];
  const int tid = threadIdx.x, lane = tid & 63, w = tid >> 6;
  const int lr = lane & 15, lq = lane >> 4;
  const int bid = blockIdx.x;
  const int jj = (bid & 7) * 128 + (bid >> 3);
  const int bh = jj >> 3, b = bh >> 4, h = bh & 15;
  const int ach = jj & 7;
  const int lbase = ach * (L_ / ACH);

  bf16x8 mf[5][2];
#pragma unroll
  for (int mi = 0; mi < 5; ++mi)
#pragma unroll
    for (int kh = 0; kh < 2; ++kh)
      mf[mi][kh] = *(const bf16x8*)&MP[(size_t)(h * EP + w * 80 + mi * 16 + lr) * KP + kh * 32 + lq * 8];

  if (tid < 128) {
    int buf = tid >> 6, t = tid & 63;
    uint4 z = {0, 0, 0, 0};
    *(uint4*)&Qs[buf][(t >> 1) * 88 + 48 + (t & 1) * 8] = z;
  }

  auto loadQ = [&](int idx, int l0) {
    return *(const bf16x8*)&Qb[(size_t)(b * L_ + l0 + idx / 6) * D_ + h * DH + (idx % 6) * 8];
  };
  auto loadV = [&](int j, int l0) {
    return *(const bf16x8*)&VT[((size_t)bh * DH + (j >> 2)) * L_ + l0 + (j & 3) * 8];
  };

  bf16x8 rA, rB;
  {
    int l0 = lbase;
    rA = (tid < 192) ? loadQ(tid, l0) : loadV(tid - 192, l0);
    if (tid < 128) rB = loadV(tid + 64, l0);
  }

  f32x4 acc[5][3] = {};

  for (int it = 0; it < L_ / ACH / 32; ++it) {
    const int cur = it & 1;
    if (tid < 192) *(bf16x8*)&Qs[cur][(tid / 6) * 88 + (tid % 6) * 8] = rA;
    else           *(bf16x8*)&Vs[cur][((tid - 192) >> 2) * 40 + ((tid - 192) & 3) * 8] = rA;
    if (tid < 128) *(bf16x8*)&Vs[cur][((tid + 64) >> 2) * 40 + ((tid + 64) & 3) * 8] = rB;
    __syncthreads();
    if (it + 1 < L_ / ACH / 32) {
      int l0 = lbase + (it + 1) * 32;
      rA = (tid < 192) ? loadQ(tid, l0) : loadV(tid - 192, l0);
      if (tid < 128) rB = loadV(tid + 64, l0);
    }
    bf16x8 qf[2][2];
#pragma unroll
    for (int ni = 0; ni < 2; ++ni)
#pragma unroll
      for (int kh = 0; kh < 2; ++kh)
        qf[ni][kh] = *(const bf16x8*)&Qs[cur][(ni * 16 + lr) * 88 + kh * 32 + lq * 8];
    __builtin_amdgcn_s_setprio(1);
#pragma unroll
    for (int mi = 0; mi < 5; ++mi)
#pragma unroll
      for (int ni = 0; ni < 2; ++ni) {
        f32x4 s = {0.f, 0.f, 0.f, 0.f};
        s = mfma16(mf[mi][0], qf[ni][0], s);
        s = mfma16(mf[mi][1], qf[ni][1], s);
#pragma unroll
        for (int r = 0; r < 4; ++r)
          Ss[(w * 80 + mi * 16 + lq * 4 + r) * 40 + ni * 16 + lr] =
              (bf16)(s[r] > 0.f ? s[r] : 0.f);
      }
    __builtin_amdgcn_s_setprio(0);
    bf16x8 sf[5], vf[3];
#pragma unroll
    for (int mi = 0; mi < 5; ++mi)
      sf[mi] = *(const bf16x8*)&Ss[(w * 80 + mi * 16 + lr) * 40 + lq * 8];
#pragma unroll
    for (int ni = 0; ni < 3; ++ni)
      vf[ni] = *(const bf16x8*)&Vs[cur][(ni * 16 + lr) * 40 + lq * 8];
    __builtin_amdgcn_s_setprio(1);
#pragma unroll
    for (int mi = 0; mi < 5; ++mi)
#pragma unroll
      for (int ni = 0; ni < 3; ++ni)
        acc[mi][ni] = mfma16(sf[mi], vf[ni], acc[mi][ni]);
    __builtin_amdgcn_s_setprio(0);
  }
  bf16* dst = O1P + (size_t)(ach * 128 + bh) * DH * EP;
#pragma unroll
  for (int mi = 0; mi < 5; ++mi)
#pragma unroll
    for (int ni = 0; ni < 3; ++ni) {
      int e = w * 80 + mi * 16 + lq * 4;
      int d = ni * 16 + lr;
      bf16x4 v;
#pragma unroll
      for (int r = 0; r < 4; ++r) v[r] = (bf16)acc[mi][ni][r];
      *(bf16x4*)&dst[(size_t)d * EP + e] = v;
    }
}

// ---- reduce bf16 partials -> O1T bf16 [bh][d][320], vectorized x8 ----
__global__ __launch_bounds__(256) void k_red(const bf16* __restrict__ O1P,
                                             bf16* __restrict__ O1T) {
  int i8 = blockIdx.x * 256 + threadIdx.x;
  if (i8 >= N1T / 8) return;
  float s[8] = {};
#pragma unroll
  for (int c = 0; c < ACH; ++c) {
    bf16x8 v = *(const bf16x8*)&O1P[(size_t)c * N1T + (size_t)i8 * 8];
#pragma unroll
    for (int j = 0; j < 8; ++j) s[j] += (float)v[j];
  }
  bf16x8 o;
#pragma unroll
  for (int j = 0; j < 8; ++j) o[j] = (bf16)s[j];
  *(bf16x8*)&O1T[(size_t)i8 * 8] = o;
}

// ---- phase B: x = relu(Q @ mem^T) @ out1, e-chunked (5 x 64) ----
// 1D grid 4096 = 8 XCDs x 512; same-bh l-tiles grouped per XCD (O1T +
// mem head slice L2-resident per XCD).
__global__ __launch_bounds__(256, 4) void k_phaseB(
    const bf16* __restrict__ Qb, const bf16* __restrict__ MP,
    const bf16* __restrict__ O1T, bf16* __restrict__ X) {
  __shared__ bf16 Qs[64 * 88];
  __shared__ bf16 STs[64 * 76];
  __shared__ bf16 O1s[2][48 * 76];
  const int tid = threadIdx.x, lane = tid & 63, w = tid >> 6;
  const int lr = lane & 15, lq = lane >> 4;
  const int bid = blockIdx.x;
  const int jj = (bid & 7) * 512 + (bid >> 3);
  const int bh = jj >> 5, b = bh >> 4, h = bh & 15;
  const int l0 = (jj & 31) * 64;

  bf16x8 mfB[5][2];
#pragma unroll
  for (int c = 0; c < 5; ++c)
#pragma unroll
    for (int kh = 0; kh < 2; ++kh)
      mfB[c][kh] = *(const bf16x8*)&MP[(size_t)(h * EP + c * 64 + w * 16 + lr) * KP + kh * 32 + lq * 8];

  for (int idx = tid; idx < 512; idx += 256) {
    if (idx < 384) {
      int row = idx / 6, c = idx % 6;
      *(bf16x8*)&Qs[row * 88 + c * 8] =
          *(const bf16x8*)&Qb[(size_t)(b * L_ + l0 + row) * D_ + h * DH + c * 8];
    } else {
      int j = idx - 384;
      uint4 z = {0, 0, 0, 0};
      *(uint4*)&Qs[(j >> 1) * 88 + 48 + (j & 1) * 8] = z;
    }
  }
  for (int idx = tid; idx < 384; idx += 256)
    *(bf16x8*)&O1s[0][(idx >> 3) * 76 + (idx & 7) * 8] =
        *(const bf16x8*)&O1T[((size_t)bh * DH + (idx >> 3)) * EP + (idx & 7) * 8];
  __syncthreads();

  f32x4 acc[3] = {};
#pragma unroll
  for (int c = 0; c < 5; ++c) {
    bf16x8 r0, r1;
    if (c < 4) {
      r0 = *(const bf16x8*)&O1T[((size_t)bh * DH + (tid >> 3)) * EP + (c + 1) * 64 + (tid & 7) * 8];
      if (tid < 128) {
        int i2 = tid + 256;
        r1 = *(const bf16x8*)&O1T[((size_t)bh * DH + (i2 >> 3)) * EP + (c + 1) * 64 + (i2 & 7) * 8];
      }
    }
    __builtin_amdgcn_s_setprio(1);
#pragma unroll
    for (int mi = 0; mi < 4; ++mi) {
      bf16x8 qa0 = *(const bf16x8*)&Qs[(mi * 16 + lr) * 88 + lq * 8];
      bf16x8 qa1 = *(const bf16x8*)&Qs[(mi * 16 + lr) * 88 + 32 + lq * 8];
      f32x4 s = {0.f, 0.f, 0.f, 0.f};
      s = mfma16(qa0, mfB[c][0], s);
      s = mfma16(qa1, mfB[c][1], s);
#pragma unroll
      for (int r = 0; r < 4; ++r)
        STs[(mi * 16 + lq * 4 + r) * 76 + w * 16 + lr] =
            (bf16)(s[r] > 0.f ? s[r] : 0.f);
    }
    __builtin_amdgcn_s_setprio(0);
    __syncthreads();
    __builtin_amdgcn_s_setprio(1);
#pragma unroll
    for (int ks = 0; ks < 2; ++ks) {
      bf16x8 sf = *(const bf16x8*)&STs[(w * 16 + lr) * 76 + ks * 32 + lq * 8];
#pragma unroll
      for (int ni = 0; ni < 3; ++ni) {
        bf16x8 of = *(const bf16x8*)&O1s[c & 1][(ni * 16 + lr) * 76 + ks * 32 + lq * 8];
        acc[ni] = mfma16(sf, of, acc[ni]);
      }
    }
    __builtin_amdgcn_s_setprio(0);
    if (c < 4) {
      *(bf16x8*)&O1s[(c + 1) & 1][(tid >> 3) * 76 + (tid & 7) * 8] = r0;
      if (tid < 128) {
        int i2 = tid + 256;
        *(bf16x8*)&O1s[(c + 1) & 1][(i2 >> 3) * 76 + (i2 & 7) * 8] = r1;
      }
    }
    __syncthreads();
  }
#pragma unroll
  for (int ni = 0; ni < 3; ++ni)
#pragma unroll
    for (int r = 0; r < 4; ++r)
      X[(size_t)(b * L_ + l0 + w * 16 + lq * 4 + r) * D_ + h * DH + ni * 16 + lr] =
          (bf16)acc[ni][r];
}

// ---- LayerNorm over D=768, eps=1e-3: 1 wave per row, vectorized ----
__global__ __launch_bounds__(256) void k_ln(
    const bf16* __restrict__ X, const float* __restrict__ gamma,
    const float* __restrict__ beta, float* __restrict__ out) {
  const int lane = threadIdx.x & 63;
  const int row = blockIdx.x * 4 + (threadIdx.x >> 6);
  const bf16* x = X + (size_t)row * D_;
  float v[12];
#pragma unroll
  for (int c = 0; c < 3; ++c) {
    bf16x4 ch = *(const bf16x4*)(x + lane * 12 + c * 4);
#pragma unroll
    for (int j = 0; j < 4; ++j) v[c * 4 + j] = (float)ch[j];
  }
  float s = 0.f, q = 0.f;
#pragma unroll
  for (int j = 0; j < 12; ++j) { s += v[j]; q += v[j] * v[j]; }
#pragma unroll
  for (int off = 32; off > 0; off >>= 1) {
    s += __shfl_xor(s, off);
    q += __shfl_xor(q, off);
  }
  float mean = s * (1.f / 768.f);
  float var = q * (1.f / 768.f) - mean * mean;
  float inv = rsqrtf(var + 1e-3f);
  float* o = out + (size_t)row * D_;
#pragma unroll
  for (int c = 0; c < 3; ++c) {
    float4 g = *(const float4*)(gamma + lane * 12 + c * 4);
    float4 bt = *(const float4*)(beta + lane * 12 + c * 4);
    float4 r;
    r.x = (v[c * 4 + 0] - mean) * inv * g.x + bt.x;
    r.y = (v[c * 4 + 1] - mean) * inv * g.y + bt.y;
    r.z = (v[c * 4 + 2] - mean) * inv * g.z + bt.z;
    r.w = (v[c * 4 + 3] - mean) * inv * g.w + bt.w;
    *(float4*)(o + lane * 12 + c * 4) = r;
  }
}

extern "C" void kernel_launch(void* const* d_in, const int* in_sizes, int n_in,
                              void* d_out, int out_size, void* d_ws, size_t ws_size,
                              hipStream_t stream) {
  (void)in_sizes; (void)n_in; (void)out_size; (void)ws_size;
  const float* q_in = (const float*)d_in[0];
  const float* k_in = (const float*)d_in[1];
  const float* Wq   = (const float*)d_in[3];
  const float* bq   = (const float*)d_in[4];
  const float* Wv   = (const float*)d_in[5];
  const float* bv   = (const float*)d_in[6];
  const float* mem  = (const float*)d_in[7];
  const float* gam  = (const float*)d_in[8];
  const float* bet  = (const float*)d_in[9];
  float* out = (float*)d_out;

  char* ws = (char*)d_ws;
  size_t off = 0;
  auto alloc = [&](size_t bytes) {
    char* p = ws + off;
    off += (bytes + 255) & ~(size_t)255;
    return p;
  };
  bf16*  WqT = (bf16*)alloc((size_t)D_ * D_ * 2);
  bf16*  WvT = (bf16*)alloc((size_t)D_ * D_ * 2);
  bf16*  MP  = (bf16*)alloc((size_t)H_ * EP * KP * 2);
  bf16*  Qb  = (bf16*)alloc((size_t)B_ * L_ * D_ * 2);
  bf16*  VT  = (bf16*)alloc((size_t)B_ * H_ * DH * L_ * 2);
  bf16*  O1T = (bf16*)alloc((size_t)N1T * 2);
  // big region, time-multiplexed:
  //   {qc,kc} (cast->gemm) -> O1P bf16 (phaseA->red) -> Xb (phaseB->ln)
  const size_t castHalf  = ((size_t)B_ * L_ * D_ * 2 + 256) & ~(size_t)255;
  const size_t castBytes = 2 * castHalf;
  const size_t o1pBytes  = (size_t)ACH * N1T * 2;
  size_t bigBytes = castBytes > o1pBytes ? castBytes : o1pBytes;
  char*  big = alloc(bigBytes);
  bf16*  qc  = (bf16*)big;
  bf16*  kc  = (bf16*)(big + castHalf);
  bf16*  O1P = (bf16*)big;
  bf16*  Xb  = (bf16*)big;

  k_cast<<<dim3(2048, 2), 256, 0, stream>>>(q_in, k_in, qc, kc);
  k_prep<<<5888, 256, 0, stream>>>(Wq, Wv, mem, WqT, WvT, MP);
  k_gemm<<<dim3(768, 2), 256, 0, stream>>>(qc, kc, WqT, WvT, bq, bv, Qb, VT);
  k_phaseA<<<1024, 256, 0, stream>>>(Qb, VT, MP, O1P);
  k_red<<<(N1T / 8 + 255) / 256, 256, 0, stream>>>(O1P, O1T);
  k_phaseB<<<4096, 256, 0, stream>>>(Qb, MP, O1T, Xb);
  k_ln<<<(B_ * L_) / 4, 256, 0, stream>>>(Xb, gam, bet, out);
}

// Round 11
// 187.980 us; speedup vs baseline: 1.0209x; 1.0209x over previous
//
#include <hip/hip_runtime.h>
#include <hip/hip_bf16.h>
#include <stdint.h>

#define B_   8
#define L_   2048
#define D_   768
#define H_   16
#define DH   48
#define E_   300
#define EP   320   // E padded to 320 (zeros -> relu(0)=0, exact no-op)
#define KP   64    // dh padded to 64 for K of MFMA1
#define ACH  8     // phaseA L-chunks
#define N1T  (128 * DH * EP)   // one partial-out1 plane
#define NT_  24    // GEMM K-steps (768/32)

typedef __bf16 bf16;
typedef __bf16 bf16x8 __attribute__((ext_vector_type(8)));
typedef __bf16 bf16x4 __attribute__((ext_vector_type(4)));
typedef float  f32x4  __attribute__((ext_vector_type(4)));

typedef const __attribute__((address_space(1))) uint32_t guint;
typedef __attribute__((address_space(3))) uint32_t luint;

__device__ __forceinline__ f32x4 mfma16(bf16x8 a, bf16x8 b, f32x4 c) {
  return __builtin_amdgcn_mfma_f32_16x16x32_bf16(a, b, c, 0, 0, 0);
}

// ---- prep (merged): W transpose-cast x2 + memory pad, one launch ----
__global__ __launch_bounds__(256) void k_prep(
    const float* __restrict__ Wq, const float* __restrict__ Wv,
    const float* __restrict__ M, bf16* __restrict__ WqT,
    bf16* __restrict__ WvT, bf16* __restrict__ MP) {
  int bid = blockIdx.x;
  if (bid < 4608) {                       // 2 x 2304: W transpose-cast
    int which = bid / 2304;
    int idx = (bid % 2304) * 256 + threadIdx.x;
    int n = idx / D_, k = idx % D_;
    const float* W = which ? Wv : Wq;
    bf16* WT = which ? WvT : WqT;
    WT[n * D_ + k] = (bf16)W[k * D_ + n];
  } else {                                // 1280: memory -> MP [h][320][64]
    int idx = (bid - 4608) * 256 + threadIdx.x;
    int h = idx / (EP * KP);
    int r = idx % (EP * KP);
    int e = r / KP, d = r % KP;
    float v = (e < E_ && d < DH) ? M[(e * H_ + h) * DH + d] : 0.f;
    MP[idx] = (bf16)v;
  }
}

// ---- projection GEMM: C[16384x768] = cvt(A fp32) @ W + bias ----
// 256 thr / 4 waves (2x2), 64x64/wave. BM=BN=128, BK=32. 3-deep LDS (48KB,
// 3 blocks/CU). A: fp32 reg-loads (2 iters ahead) + cvt + swizzled ds_write;
// B: global_load_lds, pre-swizzled source. Commit of A(t+1) auto-vmcnt
// retires exactly {.., stageB(t), A(t+1)} (issue order pinned by
// sched_barrier), keeping stageB(t+1)/A(t+2)/stageB(t+2)/A(t+3) in flight
// across the raw lgkm-only barrier. XOR slot swizzle both sides.
__global__ __launch_bounds__(256, 3) void k_gemm(
    const float* __restrict__ A0, const float* __restrict__ A1,
    const bf16* __restrict__ WT0, const bf16* __restrict__ WT1,
    const float* __restrict__ b0, const float* __restrict__ b1,
    bf16* __restrict__ outQ, bf16* __restrict__ outVT) {
  __shared__ bf16 As[3][128 * 32];   // 3 x 8 KB
  __shared__ bf16 Bs[3][128 * 32];   // 3 x 8 KB
  const int tid = threadIdx.x, lane = tid & 63, w = tid >> 6;
  const int wr = w >> 1, wc = w & 1;
  const int lr = lane & 15, lq = lane >> 4;
  // XCD-chunked swizzle: 768 = 8 XCDs x 96 (bijective); an m-panel's 6
  // n-blocks run consecutively on one XCD -> fp32 A panel (384KB) L2-hot.
  const int bid = blockIdx.x;
  const int j = (bid & 7) * 96 + (bid >> 3);
  const int n0 = (j % 6) * 128, m0 = (j / 6) * 128;
  const int mode = blockIdx.y;
  const float* A = mode ? A1 : A0;
  const bf16* WT = mode ? WT1 : WT0;
  const float* bias = mode ? b1 : b0;

  // A thread mapping: idx in {tid, tid+256}; row=idx>>2, logical chunk=idx&3
  const int arow = tid >> 2, ac = tid & 3;
  const int aslot = ac ^ ((arow >> 1) & 3);   // same swizzle for row+64
  const float* aSrc = A + (size_t)(m0 + arow) * D_ + ac * 8;

  auto stageB = [&](int buf, int k0) {
#pragma unroll
    for (int p = 0; p < 2; ++p) {
      int idx = tid + p * 256;
      int row = idx >> 2, ct = idx & 3;
      int gc = ct ^ ((row >> 1) & 3);          // pre-swizzled source chunk
      const bf16* src = WT + (size_t)(n0 + row) * D_ + k0 + gc * 8;
      __builtin_amdgcn_global_load_lds((guint*)src,
          (luint*)&Bs[buf][(p * 256 + w * 64) * 8], 16, 0, 0);
    }
  };

  f32x4 acc[4][4] = {};
  float4 ar[3][4];   // 3 generations x 16 floats (static indices only)

#define LOADA(G, T)                                                \
  { const float* s0_ = aSrc + (T) * 32;                            \
    ar[G][0] = *(const float4*)s0_;                                \
    ar[G][1] = *(const float4*)(s0_ + 4);                          \
    const float* s1_ = s0_ + (size_t)64 * D_;                      \
    ar[G][2] = *(const float4*)s1_;                                \
    ar[G][3] = *(const float4*)(s1_ + 4); }
#define COMMITA(G, BUF)                                            \
  { bf16x8 v_;                                                     \
    v_[0]=(bf16)ar[G][0].x; v_[1]=(bf16)ar[G][0].y;                \
    v_[2]=(bf16)ar[G][0].z; v_[3]=(bf16)ar[G][0].w;                \
    v_[4]=(bf16)ar[G][1].x; v_[5]=(bf16)ar[G][1].y;                \
    v_[6]=(bf16)ar[G][1].z; v_[7]=(bf16)ar[G][1].w;                \
    *(bf16x8*)&As[BUF][arow * 32 + aslot * 8] = v_;                \
    v_[0]=(bf16)ar[G][2].x; v_[1]=(bf16)ar[G][2].y;                \
    v_[2]=(bf16)ar[G][2].z; v_[3]=(bf16)ar[G][2].w;                \
    v_[4]=(bf16)ar[G][3].x; v_[5]=(bf16)ar[G][3].y;                \
    v_[6]=(bf16)ar[G][3].z; v_[7]=(bf16)ar[G][3].w;                \
    *(bf16x8*)&As[BUF][(arow + 64) * 32 + aslot * 8] = v_; }
#define SBAR __builtin_amdgcn_sched_barrier(0)

  // prologue (order pinned: loadA(s) < stageB(s) < loadA(s+1)):
  LOADA(0, 0);  SBAR;
  stageB(0, 0); SBAR;
  LOADA(1, 1);  SBAR;
  stageB(1, 32); SBAR;
  LOADA(2, 2);  SBAR;
  COMMITA(0, 0);          // auto-wait retires A(0) only; B(0),A(1),B(1),A(2) fly

#pragma unroll
  for (int t = 0; t < NT_; ++t) {
    const int cur = t % 3;
    if (t + 1 < NT_) { COMMITA((t + 1) % 3, (t + 1) % 3); }  // auto-vmcnt retires ..stageB(t),A(t+1)
    else { asm volatile("s_waitcnt vmcnt(0)" ::: "memory"); }
    asm volatile("s_waitcnt lgkmcnt(0)" ::: "memory");
    __builtin_amdgcn_s_barrier();
    SBAR;
    if (t + 2 < NT_) stageB((t + 2) % 3, (t + 2) * 32);
    SBAR;                                  // pin: stageB(t+2) before loadA(t+3)
    if (t + 3 < NT_) LOADA(t % 3, t + 3);
    SBAR;

    bf16x8 af[4], bfr[4];
#pragma unroll
    for (int mi = 0; mi < 4; ++mi) {
      int row = wr * 64 + mi * 16 + lr;
      af[mi] = *(const bf16x8*)&As[cur][row * 32 + ((lq ^ ((row >> 1) & 3)) * 8)];
    }
#pragma unroll
    for (int ni = 0; ni < 4; ++ni) {
      int row = wc * 64 + ni * 16 + lr;
      bfr[ni] = *(const bf16x8*)&Bs[cur][row * 32 + ((lq ^ ((row >> 1) & 3)) * 8)];
    }
    __builtin_amdgcn_s_setprio(1);
#pragma unroll
    for (int mi = 0; mi < 4; ++mi)
#pragma unroll
      for (int ni = 0; ni < 4; ++ni)
        acc[mi][ni] = mfma16(af[mi], bfr[ni], acc[mi][ni]);
    __builtin_amdgcn_s_setprio(0);
  }
#undef LOADA
#undef COMMITA
#undef SBAR

  float bs[4];
#pragma unroll
  for (int ni = 0; ni < 4; ++ni) bs[ni] = bias[n0 + wc * 64 + ni * 16 + lr];

  if (mode == 0) {
#pragma unroll
    for (int mi = 0; mi < 4; ++mi)
#pragma unroll
      for (int ni = 0; ni < 4; ++ni) {
        int m = m0 + wr * 64 + mi * 16 + lq * 4;
        int n = n0 + wc * 64 + ni * 16 + lr;
#pragma unroll
        for (int r = 0; r < 4; ++r)
          outQ[(size_t)(m + r) * D_ + n] = (bf16)(acc[mi][ni][r] + bs[ni]);
      }
  } else {
#pragma unroll
    for (int mi = 0; mi < 4; ++mi)
#pragma unroll
      for (int ni = 0; ni < 4; ++ni) {
        int mb = m0 + wr * 64 + mi * 16 + lq * 4;
        int n = n0 + wc * 64 + ni * 16 + lr;
        int bhd = (mb >> 11) * H_ + n / DH;
        int d = n % DH;
        int l = mb & (L_ - 1);
        bf16x4 v;
#pragma unroll
        for (int r = 0; r < 4; ++r) v[r] = (bf16)(acc[mi][ni][r] + bs[ni]);
        *(bf16x4*)&outVT[((size_t)bhd * DH + d) * L_ + l] = v;
      }
  }
}

// ---- phase A: partial out1 = relu(mem @ Q^T) @ V over an L/8 chunk ----
// 1D grid 1024 = 8 XCDs x 128; same-bh chunks grouped per XCD.
__global__ __launch_bounds__(256) void k_phaseA(
    const bf16* __restrict__ Qb, const bf16* __restrict__ VT,
    const bf16* __restrict__ MP, bf16* __restrict__ O1P) {
  __shared__ bf16 Qs[2][32 * 88];
  __shared__ bf16 Vs[2][48 * 40];
  __shared__ bf16 Ss[EP * 40];
  const int tid = threadIdx.x, lane = tid & 63, w = tid >> 6;
  const int lr = lane & 15, lq = lane >> 4;
  const int bid = blockIdx.x;
  const int jj = (bid & 7) * 128 + (bid >> 3);
  const int bh = jj >> 3, b = bh >> 4, h = bh & 15;
  const int ach = jj & 7;
  const int lbase = ach * (L_ / ACH);

  bf16x8 mf[5][2];
#pragma unroll
  for (int mi = 0; mi < 5; ++mi)
#pragma unroll
    for (int kh = 0; kh < 2; ++kh)
      mf[mi][kh] = *(const bf16x8*)&MP[(size_t)(h * EP + w * 80 + mi * 16 + lr) * KP + kh * 32 + lq * 8];

  if (tid < 128) {
    int buf = tid >> 6, t = tid & 63;
    uint4 z = {0, 0, 0, 0};
    *(uint4*)&Qs[buf][(t >> 1) * 88 + 48 + (t & 1) * 8] = z;
  }

  auto loadQ = [&](int idx, int l0) {
    return *(const bf16x8*)&Qb[(size_t)(b * L_ + l0 + idx / 6) * D_ + h * DH + (idx % 6) * 8];
  };
  auto loadV = [&](int j, int l0) {
    return *(const bf16x8*)&VT[((size_t)bh * DH + (j >> 2)) * L_ + l0 + (j & 3) * 8];
  };

  bf16x8 rA, rB;
  {
    int l0 = lbase;
    rA = (tid < 192) ? loadQ(tid, l0) : loadV(tid - 192, l0);
    if (tid < 128) rB = loadV(tid + 64, l0);
  }

  f32x4 acc[5][3] = {};

  for (int it = 0; it < L_ / ACH / 32; ++it) {
    const int cur = it & 1;
    if (tid < 192) *(bf16x8*)&Qs[cur][(tid / 6) * 88 + (tid % 6) * 8] = rA;
    else           *(bf16x8*)&Vs[cur][((tid - 192) >> 2) * 40 + ((tid - 192) & 3) * 8] = rA;
    if (tid < 128) *(bf16x8*)&Vs[cur][((tid + 64) >> 2) * 40 + ((tid + 64) & 3) * 8] = rB;
    __syncthreads();
    if (it + 1 < L_ / ACH / 32) {
      int l0 = lbase + (it + 1) * 32;
      rA = (tid < 192) ? loadQ(tid, l0) : loadV(tid - 192, l0);
      if (tid < 128) rB = loadV(tid + 64, l0);
    }
    bf16x8 qf[2][2];
#pragma unroll
    for (int ni = 0; ni < 2; ++ni)
#pragma unroll
      for (int kh = 0; kh < 2; ++kh)
        qf[ni][kh] = *(const bf16x8*)&Qs[cur][(ni * 16 + lr) * 88 + kh * 32 + lq * 8];
    __builtin_amdgcn_s_setprio(1);
#pragma unroll
    for (int mi = 0; mi < 5; ++mi)
#pragma unroll
      for (int ni = 0; ni < 2; ++ni) {
        f32x4 s = {0.f, 0.f, 0.f, 0.f};
        s = mfma16(mf[mi][0], qf[ni][0], s);
        s = mfma16(mf[mi][1], qf[ni][1], s);
#pragma unroll
        for (int r = 0; r < 4; ++r)
          Ss[(w * 80 + mi * 16 + lq * 4 + r) * 40 + ni * 16 + lr] =
              (bf16)(s[r] > 0.f ? s[r] : 0.f);
      }
    __builtin_amdgcn_s_setprio(0);
    bf16x8 sf[5], vf[3];
#pragma unroll
    for (int mi = 0; mi < 5; ++mi)
      sf[mi] = *(const bf16x8*)&Ss[(w * 80 + mi * 16 + lr) * 40 + lq * 8];
#pragma unroll
    for (int ni = 0; ni < 3; ++ni)
      vf[ni] = *(const bf16x8*)&Vs[cur][(ni * 16 + lr) * 40 + lq * 8];
    __builtin_amdgcn_s_setprio(1);
#pragma unroll
    for (int mi = 0; mi < 5; ++mi)
#pragma unroll
      for (int ni = 0; ni < 3; ++ni)
        acc[mi][ni] = mfma16(sf[mi], vf[ni], acc[mi][ni]);
    __builtin_amdgcn_s_setprio(0);
  }
  bf16* dst = O1P + (size_t)(ach * 128 + bh) * DH * EP;
#pragma unroll
  for (int mi = 0; mi < 5; ++mi)
#pragma unroll
    for (int ni = 0; ni < 3; ++ni) {
      int e = w * 80 + mi * 16 + lq * 4;
      int d = ni * 16 + lr;
      bf16x4 v;
#pragma unroll
      for (int r = 0; r < 4; ++r) v[r] = (bf16)acc[mi][ni][r];
      *(bf16x4*)&dst[(size_t)d * EP + e] = v;
    }
}

// ---- reduce bf16 partials -> O1T bf16 [bh][d][320], vectorized x8 ----
__global__ __launch_bounds__(256) void k_red(const bf16* __restrict__ O1P,
                                             bf16* __restrict__ O1T) {
  int i8 = blockIdx.x * 256 + threadIdx.x;
  if (i8 >= N1T / 8) return;
  float s[8] = {};
#pragma unroll
  for (int c = 0; c < ACH; ++c) {
    bf16x8 v = *(const bf16x8*)&O1P[(size_t)c * N1T + (size_t)i8 * 8];
#pragma unroll
    for (int j = 0; j < 8; ++j) s[j] += (float)v[j];
  }
  bf16x8 o;
#pragma unroll
  for (int j = 0; j < 8; ++j) o[j] = (bf16)s[j];
  *(bf16x8*)&O1T[(size_t)i8 * 8] = o;
}

// ---- phase B: x = relu(Q @ mem^T) @ out1, e-chunked (5 x 64) ----
// 1D grid 4096 = 8 XCDs x 512; same-bh l-tiles grouped per XCD.
__global__ __launch_bounds__(256, 4) void k_phaseB(
    const bf16* __restrict__ Qb, const bf16* __restrict__ MP,
    const bf16* __restrict__ O1T, bf16* __restrict__ X) {
  __shared__ bf16 Qs[64 * 88];
  __shared__ bf16 STs[64 * 76];
  __shared__ bf16 O1s[2][48 * 76];
  const int tid = threadIdx.x, lane = tid & 63, w = tid >> 6;
  const int lr = lane & 15, lq = lane >> 4;
  const int bid = blockIdx.x;
  const int jj = (bid & 7) * 512 + (bid >> 3);
  const int bh = jj >> 5, b = bh >> 4, h = bh & 15;
  const int l0 = (jj & 31) * 64;

  bf16x8 mfB[5][2];
#pragma unroll
  for (int c = 0; c < 5; ++c)
#pragma unroll
    for (int kh = 0; kh < 2; ++kh)
      mfB[c][kh] = *(const bf16x8*)&MP[(size_t)(h * EP + c * 64 + w * 16 + lr) * KP + kh * 32 + lq * 8];

  for (int idx = tid; idx < 512; idx += 256) {
    if (idx < 384) {
      int row = idx / 6, c = idx % 6;
      *(bf16x8*)&Qs[row * 88 + c * 8] =
          *(const bf16x8*)&Qb[(size_t)(b * L_ + l0 + row) * D_ + h * DH + c * 8];
    } else {
      int j = idx - 384;
      uint4 z = {0, 0, 0, 0};
      *(uint4*)&Qs[(j >> 1) * 88 + 48 + (j & 1) * 8] = z;
    }
  }
  for (int idx = tid; idx < 384; idx += 256)
    *(bf16x8*)&O1s[0][(idx >> 3) * 76 + (idx & 7) * 8] =
        *(const bf16x8*)&O1T[((size_t)bh * DH + (idx >> 3)) * EP + (idx & 7) * 8];
  __syncthreads();

  f32x4 acc[3] = {};
#pragma unroll
  for (int c = 0; c < 5; ++c) {
    bf16x8 r0, r1;
    if (c < 4) {
      r0 = *(const bf16x8*)&O1T[((size_t)bh * DH + (tid >> 3)) * EP + (c + 1) * 64 + (tid & 7) * 8];
      if (tid < 128) {
        int i2 = tid + 256;
        r1 = *(const bf16x8*)&O1T[((size_t)bh * DH + (i2 >> 3)) * EP + (c + 1) * 64 + (i2 & 7) * 8];
      }
    }
    __builtin_amdgcn_s_setprio(1);
#pragma unroll
    for (int mi = 0; mi < 4; ++mi) {
      bf16x8 qa0 = *(const bf16x8*)&Qs[(mi * 16 + lr) * 88 + lq * 8];
      bf16x8 qa1 = *(const bf16x8*)&Qs[(mi * 16 + lr) * 88 + 32 + lq * 8];
      f32x4 s = {0.f, 0.f, 0.f, 0.f};
      s = mfma16(qa0, mfB[c][0], s);
      s = mfma16(qa1, mfB[c][1], s);
#pragma unroll
      for (int r = 0; r < 4; ++r)
        STs[(mi * 16 + lq * 4 + r) * 76 + w * 16 + lr] =
            (bf16)(s[r] > 0.f ? s[r] : 0.f);
    }
    __builtin_amdgcn_s_setprio(0);
    __syncthreads();
    __builtin_amdgcn_s_setprio(1);
#pragma unroll
    for (int ks = 0; ks < 2; ++ks) {
      bf16x8 sf = *(const bf16x8*)&STs[(w * 16 + lr) * 76 + ks * 32 + lq * 8];
#pragma unroll
      for (int ni = 0; ni < 3; ++ni) {
        bf16x8 of = *(const bf16x8*)&O1s[c & 1][(ni * 16 + lr) * 76 + ks * 32 + lq * 8];
        acc[ni] = mfma16(sf, of, acc[ni]);
      }
    }
    __builtin_amdgcn_s_setprio(0);
    if (c < 4) {
      *(bf16x8*)&O1s[(c + 1) & 1][(tid >> 3) * 76 + (tid & 7) * 8] = r0;
      if (tid < 128) {
        int i2 = tid + 256;
        *(bf16x8*)&O1s[(c + 1) & 1][(i2 >> 3) * 76 + (i2 & 7) * 8] = r1;
      }
    }
    __syncthreads();
  }
#pragma unroll
  for (int ni = 0; ni < 3; ++ni)
#pragma unroll
    for (int r = 0; r < 4; ++r)
      X[(size_t)(b * L_ + l0 + w * 16 + lq * 4 + r) * D_ + h * DH + ni * 16 + lr] =
          (bf16)acc[ni][r];
}

// ---- LayerNorm over D=768, eps=1e-3: 1 wave per row, vectorized ----
__global__ __launch_bounds__(256) void k_ln(
    const bf16* __restrict__ X, const float* __restrict__ gamma,
    const float* __restrict__ beta, float* __restrict__ out) {
  const int lane = threadIdx.x & 63;
  const int row = blockIdx.x * 4 + (threadIdx.x >> 6);
  const bf16* x = X + (size_t)row * D_;
  float v[12];
#pragma unroll
  for (int c = 0; c < 3; ++c) {
    bf16x4 ch = *(const bf16x4*)(x + lane * 12 + c * 4);
#pragma unroll
    for (int j = 0; j < 4; ++j) v[c * 4 + j] = (float)ch[j];
  }
  float s = 0.f, q = 0.f;
#pragma unroll
  for (int j = 0; j < 12; ++j) { s += v[j]; q += v[j] * v[j]; }
#pragma unroll
  for (int off = 32; off > 0; off >>= 1) {
    s += __shfl_xor(s, off);
    q += __shfl_xor(q, off);
  }
  float mean = s * (1.f / 768.f);
  float var = q * (1.f / 768.f) - mean * mean;
  float inv = rsqrtf(var + 1e-3f);
  float* o = out + (size_t)row * D_;
#pragma unroll
  for (int c = 0; c < 3; ++c) {
    float4 g = *(const float4*)(gamma + lane * 12 + c * 4);
    float4 bt = *(const float4*)(beta + lane * 12 + c * 4);
    float4 r;
    r.x = (v[c * 4 + 0] - mean) * inv * g.x + bt.x;
    r.y = (v[c * 4 + 1] - mean) * inv * g.y + bt.y;
    r.z = (v[c * 4 + 2] - mean) * inv * g.z + bt.z;
    r.w = (v[c * 4 + 3] - mean) * inv * g.w + bt.w;
    *(float4*)(o + lane * 12 + c * 4) = r;
  }
}

extern "C" void kernel_launch(void* const* d_in, const int* in_sizes, int n_in,
                              void* d_out, int out_size, void* d_ws, size_t ws_size,
                              hipStream_t stream) {
  (void)in_sizes; (void)n_in; (void)out_size; (void)ws_size;
  const float* q_in = (const float*)d_in[0];
  const float* k_in = (const float*)d_in[1];
  const float* Wq   = (const float*)d_in[3];
  const float* bq   = (const float*)d_in[4];
  const float* Wv   = (const float*)d_in[5];
  const float* bv   = (const float*)d_in[6];
  const float* mem  = (const float*)d_in[7];
  const float* gam  = (const float*)d_in[8];
  const float* bet  = (const float*)d_in[9];
  float* out = (float*)d_out;

  char* ws = (char*)d_ws;
  size_t off = 0;
  auto alloc = [&](size_t bytes) {
    char* p = ws + off;
    off += (bytes + 255) & ~(size_t)255;
    return p;
  };
  bf16*  WqT = (bf16*)alloc((size_t)D_ * D_ * 2);
  bf16*  WvT = (bf16*)alloc((size_t)D_ * D_ * 2);
  bf16*  MP  = (bf16*)alloc((size_t)H_ * EP * KP * 2);
  bf16*  Qb  = (bf16*)alloc((size_t)B_ * L_ * D_ * 2);
  bf16*  VT  = (bf16*)alloc((size_t)B_ * H_ * DH * L_ * 2);
  bf16*  O1T = (bf16*)alloc((size_t)N1T * 2);
  // big region, time-multiplexed: O1P bf16 (phaseA->red) -> Xb (phaseB->ln)
  const size_t o1pBytes = (size_t)ACH * N1T * 2;
  const size_t xbBytes  = (size_t)B_ * L_ * D_ * 2;
  char*  big = alloc(o1pBytes > xbBytes ? o1pBytes : xbBytes);
  bf16*  O1P = (bf16*)big;
  bf16*  Xb  = (bf16*)big;

  k_prep<<<5888, 256, 0, stream>>>(Wq, Wv, mem, WqT, WvT, MP);
  k_gemm<<<dim3(768, 2), 256, 0, stream>>>(q_in, k_in, WqT, WvT, bq, bv, Qb, VT);
  k_phaseA<<<1024, 256, 0, stream>>>(Qb, VT, MP, O1P);
  k_red<<<(N1T / 8 + 255) / 256, 256, 0, stream>>>(O1P, O1T);
  k_phaseB<<<4096, 256, 0, stream>>>(Qb, MP, O1T, Xb);
  k_ln<<<(B_ * L_) / 4, 256, 0, stream>>>(Xb, gam, bet, out);
}